// Round 11
// baseline (155.865 us; speedup 1.0000x reference)
//
#include <hip/hip_runtime.h>

#define KS 21
#define CC 10
#define H 128
#define W 128
#define HW (H*W)
#define NCH 3
#define B 4
#define PW (W + 2*CC)   // 148
#define S 7             // i-row splits
#define CH 3            // i-rows per split

// kt: 63 rows x 152 f16 slots (value for px at slot px+12; slots 0..11 and
// 140..151 zero pads). Row stride 304 B. Tap (ii,j) e-read byte:
//   (ii*21+j)*304 + 2j + 4 + 2x
// dt: [CH][PW] of half4v {d0,d1,d2,0} (8 B/pixel). Tap data-read byte:
//   ii*1184 + (x+j)*8
#define KT_BYTES (63*304)            // 19152
#define DT_BYTES (CH*PW*8)           // 3552
typedef _Float16 half4v __attribute__((ext_vector_type(4)));

template<int II, int J0, int J1>
__device__ __forceinline__ void taps(const unsigned char* __restrict__ kp,
                                     const unsigned char* __restrict__ dp,
                                     float& a0, float& a1, float& a2, float& aw)
{
    #pragma unroll
    for (int j = J0; j < J1; ++j) {
        _Float16 e16 = *reinterpret_cast<const _Float16*>(
            kp + (II * 21 + j) * 304 + 2 * j + 4);          // imm offset
        half4v dv = *reinterpret_cast<const half4v*>(
            dp + II * 1184 + j * 8);                        // imm offset
        float e = (float)e16;
        a0 += e * (float)dv.x;
        a1 += e * (float)dv.y;
        a2 += e * (float)dv.z;
        aw += e;
    }
}

// grid (H, B, S), block 256. Fully fused: each block computes one (y,b,s)
// partial; the 7th block to finish a (b,y) row (device-scope counter) does
// the fixed-order s=0..6 reduction + closed-form OOB denom + divide.
// Deterministic: summation order fixed regardless of finisher identity.
__global__ __launch_bounds__(256, 6)
void kaw_fused(const float* __restrict__ data,
               const float* __restrict__ kern,
               unsigned* __restrict__ cnt,      // B*H counters, zeroed per call
               float4* __restrict__ part,
               float* __restrict__ out,
               float* __restrict__ sumw)
{
    __shared__ __align__(16) unsigned char smem[KT_BYTES + DT_BYTES];
    __shared__ int flag;
    unsigned char* ktB = smem;
    unsigned char* dtB = smem + KT_BYTES;

    const int tid  = threadIdx.x;
    const int x    = tid & 127;
    const int half = tid >> 7;              // wave-uniform
    const int y  = blockIdx.x;
    const int b  = blockIdx.y;
    const int i0 = blockIdx.z * CH;

    const float* __restrict__ kbase = kern + (size_t)b * (KS * KS) * HW;
    const float* __restrict__ dbase = data + (size_t)b * NCH * HW;

    // ---- stage kern rows: e=exp(g) as f16. 63 rows x 32 quads ----
    #pragma unroll
    for (int k = 0; k < 8; ++k) {
        int idx = tid + k * 256;
        if (idx < 63 * 32) {
            int row = idx >> 5;             // 0..62 = ii*21 + j
            int c4  = idx & 31;
            int ii  = row >= 42 ? 2 : (row >= 21 ? 1 : 0);
            int j   = row - ii * 21;
            int q   = (KS - 1 - (i0 + ii)) * KS + (KS - 1 - j);
            int py  = y + i0 + ii - CC;
            half4v hv = (half4v){(_Float16)0, (_Float16)0, (_Float16)0, (_Float16)0};
            if ((unsigned)py < (unsigned)H) {
                float4 g = *reinterpret_cast<const float4*>(
                    kbase + (size_t)q * HW + (size_t)py * W + c4 * 4);
                hv = (half4v){(_Float16)__expf(g.x), (_Float16)__expf(g.y),
                              (_Float16)__expf(g.z), (_Float16)__expf(g.w)};
            }
            *reinterpret_cast<half4v*>(ktB + row * 304 + 24 + c4 * 8) = hv;
        }
    }
    // zero the pads: slots 0..11 (bytes 0..23) and 140..151 (bytes 280..303)
    for (int p = tid; p < 63 * 12; p += 256) {
        int row = p / 12, k = p - row * 12;
        int off = row * 304 + (k < 6 ? k * 4 : 280 + (k - 6) * 4);
        *reinterpret_cast<unsigned*>(ktB + off) = 0u;
    }

    // ---- stage data rows: packed f16 {d0,d1,d2,0}, zero-filled OOB ----
    #pragma unroll
    for (int k = 0; k < 2; ++k) {
        int e = tid + k * 256;
        if (e < CH * PW) {
            int ii = e >= 2 * PW ? 2 : (e >= PW ? 1 : 0);
            int c  = e - ii * PW;
            int gy = y + i0 + ii - CC;
            int gx = c - CC;
            half4v v = (half4v){(_Float16)0, (_Float16)0, (_Float16)0, (_Float16)0};
            if ((unsigned)gy < (unsigned)H && (unsigned)gx < (unsigned)W) {
                v.x = (_Float16)dbase[(0 * H + gy) * W + gx];
                v.y = (_Float16)dbase[(1 * H + gy) * W + gx];
                v.z = (_Float16)dbase[(2 * H + gy) * W + gx];
            }
            *reinterpret_cast<half4v*>(dtB + e * 8) = v;
        }
    }
    __syncthreads();

    // ---- compute: half 0 -> j=0..10, half 1 -> j=11..20 (wave-uniform,
    // fully templated: all LDS reads are imm-offset) ----
    float a0 = 0.f, a1 = 0.f, a2 = 0.f, aw = 0.f;
    {
        const unsigned char* kp = ktB + 2 * x;
        const unsigned char* dp = dtB + 8 * x;
        if (half == 0) {
            taps<0, 0, 11>(kp, dp, a0, a1, a2, aw);
            taps<1, 0, 11>(kp, dp, a0, a1, a2, aw);
            taps<2, 0, 11>(kp, dp, a0, a1, a2, aw);
        } else {
            taps<0, 11, 21>(kp, dp, a0, a1, a2, aw);
            taps<1, 11, 21>(kp, dp, a0, a1, a2, aw);
            taps<2, 11, 21>(kp, dp, a0, a1, a2, aw);
        }
    }

    // ---- fixed-order combine: total = half0 + half1 ----
    __syncthreads();                         // kt/dt reads done; reuse dt as sred
    float* sred = (float*)dtB;               // 128*16 = 2048 <= 3552 B
    if (half == 1) {
        *reinterpret_cast<float4*>(sred + x * 4) = make_float4(a0, a1, a2, aw);
    }
    __syncthreads();
    if (half == 0) {
        float4 s = *reinterpret_cast<const float4*>(sred + x * 4);
        a0 += s.x; a1 += s.y; a2 += s.z; aw += s.w;
        part[(size_t)(blockIdx.z * B + b) * HW + (size_t)y * W + x] =
            make_float4(a0, a1, a2, aw);
    }

    // ---- elect finisher: 7th block to complete (b,y) does the reduction ----
    __syncthreads();                         // drains vmcnt -> partial stores done
    if (tid == 0) {
        __threadfence();                     // release: push partials device-wide
        flag = (int)atomicAdd(&cnt[b * H + y], 1u);
    }
    __syncthreads();
    if (flag == S - 1) {
        __threadfence();                     // acquire: invalidate stale caches
        if (half == 0) {
            float r0 = 0.f, r1 = 0.f, r2 = 0.f, rw = 0.f;
            #pragma unroll
            for (int s = 0; s < S; ++s) {    // fixed order -> deterministic
                float4 p = part[(size_t)(s * B + b) * HW + (size_t)y * W + x];
                r0 += p.x; r1 += p.y; r2 += p.z; rw += p.w;
            }
            // OOB taps contribute exp(0)=1 each to the softmax denominator
            int nry = max(0, CC - y) + max(0, y - (H - 1 - CC));
            int nrx = max(0, CC - x) + max(0, x - (W - 1 - CC));
            float co = 21.f * nry + (float)((21 - nry) * nrx);
            float inv = 1.0f / (rw + co);
            const size_t o = (size_t)b * NCH * HW + (size_t)y * W + x;
            out[o]          = r0 * inv;
            out[o + HW]     = r1 * inv;
            out[o + 2 * HW] = r2 * inv;
            sumw[(size_t)b * HW + (size_t)y * W + x] = rw * inv;
        }
    }
}

// ---------- fallback: proven monolithic kernel if ws too small --------------
#define TY 2
__global__ __launch_bounds__(256)
void kaw_mono(const float* __restrict__ data,
              const float* __restrict__ kern,
              float* __restrict__ out,
              float* __restrict__ sumw)
{
    const int x  = threadIdx.x;
    const int ty = threadIdx.y;
    const int y0 = blockIdx.x * TY;
    const int b  = blockIdx.y;
    const int y  = y0 + ty;

    __shared__ __align__(16) float sdat[TY + 2 * CC][PW][4];

    const float* __restrict__ dbase = data + (size_t)b * NCH * HW;
    const int tid = ty * W + x;
    for (int e = tid; e < (TY + 2 * CC) * PW; e += W * TY) {
        int r  = e / PW;
        int xx = e - r * PW;
        int gy = y0 + r - CC;
        int gx = xx - CC;
        float4 v = make_float4(0.f, 0.f, 0.f, 0.f);
        if ((unsigned)gy < (unsigned)H && (unsigned)gx < (unsigned)W) {
            v.x = dbase[(0 * H + gy) * W + gx];
            v.y = dbase[(1 * H + gy) * W + gx];
            v.z = dbase[(2 * H + gy) * W + gx];
        }
        *reinterpret_cast<float4*>(&sdat[r][xx][0]) = v;
    }
    __syncthreads();

    const float* __restrict__ kbase = kern + (size_t)b * (KS * KS) * HW;
    float acc0 = 0.f, acc1 = 0.f, acc2 = 0.f, accw = 0.f, accd = 0.f;

    for (int i = 0; i < KS; ++i) {
        const int py = y + i - CC;
        if ((unsigned)py >= (unsigned)H) { accd += (float)KS; continue; }
        const float* __restrict__ krow =
            kbase + (size_t)(KS - 1 - i) * KS * HW + (size_t)py * W;
        const float* __restrict__ srow = &sdat[ty + i][0][0];
        #pragma unroll
        for (int j = 0; j < KS; ++j) {
            int px = x + j - CC;
            bool vx = (unsigned)px < (unsigned)W;
            int spx = px < 0 ? 0 : (px > W - 1 ? W - 1 : px);
            float g = krow[(size_t)(KS - 1 - j) * HW + spx];
            float e = vx ? __expf(g) : 0.f;
            float4 dv = *reinterpret_cast<const float4*>(srow + (size_t)(x + j) * 4);
            acc0 += e * dv.x; acc1 += e * dv.y; acc2 += e * dv.z;
            accw += e; accd += vx ? e : 1.f;
        }
    }

    const float inv = 1.0f / accd;
    const size_t o = (size_t)b * NCH * HW + (size_t)y * W + x;
    out[o]          = acc0 * inv;
    out[o + HW]     = acc1 * inv;
    out[o + 2 * HW] = acc2 * inv;
    sumw[(size_t)b * HW + (size_t)y * W + x] = accw * inv;
}

extern "C" void kernel_launch(void* const* d_in, const int* in_sizes, int n_in,
                              void* d_out, int out_size, void* d_ws, size_t ws_size,
                              hipStream_t stream)
{
    const float* data = (const float*)d_in[0];   // (4,3,128,128) f32
    const float* kern = (const float*)d_in[1];   // (4,441,128,128) f32
    float* out  = (float*)d_out;                 // (4,3,128,128)
    float* sumw = out + (size_t)B * NCH * HW;    // (4,1,128,128)

    // ws layout: [0, 2048) counters (B*H u32), [4096, ...) partials
    const size_t cnt_bytes = (size_t)B * H * sizeof(unsigned);          // 2 KB
    const size_t ws_need   = 4096 + (size_t)S * B * HW * sizeof(float4);
    if (ws_size >= ws_need) {
        unsigned* cnt = (unsigned*)d_ws;
        float4* part  = (float4*)((char*)d_ws + 4096);
        hipMemsetAsync(cnt, 0, cnt_bytes, stream);
        dim3 g1(H, B, S);
        kaw_fused<<<g1, 256, 0, stream>>>(data, kern, cnt, part, out, sumw);
    } else {
        dim3 g(H / TY, B), blk(W, TY);
        kaw_mono<<<g, blk, 0, stream>>>(data, kern, out, sumw);
    }
}

// Round 13
// 34.388 us; speedup vs baseline: 4.5325x; 4.5325x over previous
//
#include <hip/hip_runtime.h>

#define KS 21
#define CC 10
#define H 128
#define W 128
#define HW (H*W)
#define NCH 3
#define B 4
#define PW (W + 2*CC)          // 148

typedef _Float16 half4v __attribute__((ext_vector_type(4)));
struct __attribute__((packed)) f4u { float v[4]; };   // 4B-aligned 16B load

// LDS: dt[21][PW] packed half4 {d0,d1,d2,0} = 24864 B; sacc (8 x 129 x 16B
// = 16512 B) aliases it after a barrier.
#define DT_BYTES (21*PW*8)

// grid (H, B), block 256. Block = one output row (b,y). Worker w = tid&7
// takes flattened taps T = w, w+8, ... (<441); t = tid>>3 owns output px
// 4t..4t+3. Tap T: kern plane Q = 440-T (gather map), row py = y+i-10,
// cols c0..c0+3 with c0 = 4t+j-10 — kern load is a coalesced (4B-aligned)
// dwordx4 straight from global (each kern byte read exactly once chip-wide;
// no LDS staging, no exp re-store). Data comes from a packed-f16 LDS tile
// indexed [row i][col c0+10]. Branchless masks; epilogue does a fixed-order
// 8-worker reduce + closed-form OOB denominator + divide.
// No atomics, no fences, fully deterministic.
__global__ __launch_bounds__(256, 2)
void kaw_gather(const float* __restrict__ data,
                const float* __restrict__ kern,
                float* __restrict__ out,
                float* __restrict__ sumw)
{
    __shared__ __align__(16) unsigned char smem[DT_BYTES];
    unsigned char* dtB = smem;

    const int tid = threadIdx.x;
    const int w = tid & 7;          // tap worker
    const int t = tid >> 3;         // px quad: px = 4t..4t+3
    const int y = blockIdx.x;
    const int b = blockIdx.y;

    const float* __restrict__ kbase = kern + (size_t)b * (KS * KS) * HW;
    const float* __restrict__ dbase = data + (size_t)b * NCH * HW;

    // ---- stage data rows y-10..y+10, packed f16 {d0,d1,d2,0}, OOB=0 ----
    for (int e = tid; e < 21 * PW; e += 256) {
        int r  = (e * 7085) >> 20;          // e / 148 (exact for e < 3108)
        int c  = e - r * PW;
        int gy = y + r - CC;
        int gx = c - CC;
        half4v v = (half4v){(_Float16)0, (_Float16)0, (_Float16)0, (_Float16)0};
        if ((unsigned)gy < (unsigned)H && (unsigned)gx < (unsigned)W) {
            v.x = (_Float16)dbase[(0 * H + gy) * W + gx];
            v.y = (_Float16)dbase[(1 * H + gy) * W + gx];
            v.z = (_Float16)dbase[(2 * H + gy) * W + gx];
        }
        *reinterpret_cast<half4v*>(dtB + e * 8) = v;
    }
    __syncthreads();

    // ---- 16 accumulators: 4 px x {ch0, ch1, ch2, w} ----
    float a00 = 0.f, a01 = 0.f, a02 = 0.f, aw0 = 0.f;
    float a10 = 0.f, a11 = 0.f, a12 = 0.f, aw1 = 0.f;
    float a20 = 0.f, a21 = 0.f, a22 = 0.f, aw2 = 0.f;
    float a30 = 0.f, a31 = 0.f, a32 = 0.f, aw3 = 0.f;

    const int ntap = (w == 0) ? 56 : 55;    // T = w + 8k <= 440
    int T = w;
    #pragma unroll 4
    for (int k = 0; k < ntap; ++k, T += 8) {
        int i  = (T * 3121) >> 16;          // T / 21 (exact for T < 441)
        int j  = T - i * 21;
        int py = y + i - CC;
        bool rv = (unsigned)py < (unsigned)H;
        int pyc = py < 0 ? 0 : (py > H - 1 ? H - 1 : py);
        int c0 = 4 * t + j - CC;            // kern & data column of element 0
        // off >= 0 always (Q=0 only at T=440 where c0 = 4t+10 >= 10)
        f4u g = *reinterpret_cast<const f4u*>(
            kbase + (((440 - T) << 14) + (pyc << 7) + c0));
        float e0 = (rv && (unsigned)(c0 + 0) < (unsigned)W) ? __expf(g.v[0]) : 0.f;
        float e1 = (rv && (unsigned)(c0 + 1) < (unsigned)W) ? __expf(g.v[1]) : 0.f;
        float e2 = (rv && (unsigned)(c0 + 2) < (unsigned)W) ? __expf(g.v[2]) : 0.f;
        float e3 = (rv && (unsigned)(c0 + 3) < (unsigned)W) ? __expf(g.v[3]) : 0.f;
        // data tile: row i, col slot c0+CC  (THE round-11 bug: i*PW was missing)
        const unsigned char* dp = dtB + (unsigned)(i * PW + c0 + CC) * 8;
        half4v d0 = *reinterpret_cast<const half4v*>(dp +  0);
        half4v d1 = *reinterpret_cast<const half4v*>(dp +  8);
        half4v d2 = *reinterpret_cast<const half4v*>(dp + 16);
        half4v d3 = *reinterpret_cast<const half4v*>(dp + 24);
        a00 += e0 * (float)d0.x; a01 += e0 * (float)d0.y; a02 += e0 * (float)d0.z; aw0 += e0;
        a10 += e1 * (float)d1.x; a11 += e1 * (float)d1.y; a12 += e1 * (float)d1.z; aw1 += e1;
        a20 += e2 * (float)d2.x; a21 += e2 * (float)d2.y; a22 += e2 * (float)d2.z; aw2 += e2;
        a30 += e3 * (float)d3.x; a31 += e3 * (float)d3.y; a32 += e3 * (float)d3.z; aw3 += e3;
    }

    // ---- fixed-order cross-worker reduce (alias sacc over data tile) ----
    __syncthreads();                         // all dt reads done
    float4* sacc = (float4*)smem;            // [8][129] float4, padded stride
    sacc[w * 129 + 4 * t + 0] = make_float4(a00, a01, a02, aw0);
    sacc[w * 129 + 4 * t + 1] = make_float4(a10, a11, a12, aw1);
    sacc[w * 129 + 4 * t + 2] = make_float4(a20, a21, a22, aw2);
    sacc[w * 129 + 4 * t + 3] = make_float4(a30, a31, a32, aw3);
    __syncthreads();
    if (tid < W) {
        const int px = tid;
        float r0 = 0.f, r1 = 0.f, r2 = 0.f, rw = 0.f;
        #pragma unroll
        for (int s = 0; s < 8; ++s) {        // fixed order -> deterministic
            float4 p = sacc[s * 129 + px];
            r0 += p.x; r1 += p.y; r2 += p.z; rw += p.w;
        }
        // OOB taps contribute exp(0)=1 each to the softmax denominator
        int nry = max(0, CC - y)  + max(0, y  - (H - 1 - CC));
        int nrx = max(0, CC - px) + max(0, px - (W - 1 - CC));
        float co = 21.f * nry + (float)((21 - nry) * nrx);
        float inv = 1.0f / (rw + co);
        const size_t o = (size_t)b * NCH * HW + (size_t)y * W + px;
        out[o]          = r0 * inv;
        out[o + HW]     = r1 * inv;
        out[o + 2 * HW] = r2 * inv;
        sumw[(size_t)b * HW + (size_t)y * W + px] = rw * inv;
    }
}

extern "C" void kernel_launch(void* const* d_in, const int* in_sizes, int n_in,
                              void* d_out, int out_size, void* d_ws, size_t ws_size,
                              hipStream_t stream)
{
    const float* data = (const float*)d_in[0];   // (4,3,128,128) f32
    const float* kern = (const float*)d_in[1];   // (4,441,128,128) f32
    float* out  = (float*)d_out;                 // (4,3,128,128)
    float* sumw = out + (size_t)B * NCH * HW;    // (4,1,128,128)

    dim3 g(H, B);
    kaw_gather<<<g, 256, 0, stream>>>(data, kern, out, sumw);
}

// Round 15
// 30.664 us; speedup vs baseline: 5.0830x; 1.1215x over previous
//
#include <hip/hip_runtime.h>

#define KS 21
#define CC 10
#define H 128
#define W 128
#define HW (H*W)
#define NCH 3
#define B 4
#define HWX 64                 // half-row width per block
#define PWX (HWX + 2*CC)       // 84 data slots per staged row

typedef _Float16 half4v __attribute__((ext_vector_type(4)));
struct __attribute__((packed)) f4u { float v[4]; };   // 4B-aligned 16B load

// LDS: dt[21][PWX] packed half4 {d0,d1,d2,0} = 14112 B; sacc [16][65] float4
// = 16640 B aliases it after a barrier. Size = max of the two.
#define SMEM_BYTES (16*65*16)

// grid (H, 2, B), block 256 = 16 workers x 16 px-quads. Block = one half-row
// (b, y, x0=64*zh). Worker w takes flattened taps T = w, w+16, ... (<441);
// quad t owns px x0+4t..x0+4t+3. Tap T: kern plane Q = 440-T, row
// py = y + T/21 - 10, cols c0..c0+3 (c0 = x0+4t+(T%21)-10) — one coalesced
// dwordx4 per tap straight from global (each kern byte read once chip-wide).
// (i,j,Q) maintained incrementally (no divisions). Data from a packed-f16
// LDS tile. Epilogue: fixed-order 16-worker in-LDS reduce + closed-form OOB
// denominator + divide. No atomics, no fences, fully deterministic.
__global__ __launch_bounds__(256, 4)
void kaw_gather(const float* __restrict__ data,
                const float* __restrict__ kern,
                float* __restrict__ out,
                float* __restrict__ sumw)
{
    __shared__ __align__(16) unsigned char smem[SMEM_BYTES];
    unsigned char* dtB = smem;

    const int tid = threadIdx.x;
    const int w  = tid >> 4;        // tap worker 0..15
    const int t  = tid & 15;        // px quad within the half-row
    const int y  = blockIdx.x;
    const int x0 = blockIdx.y * HWX;
    const int b  = blockIdx.z;

    const float* __restrict__ kbase = kern + (size_t)b * (KS * KS) * HW;
    const float* __restrict__ dbase = data + (size_t)b * NCH * HW;

    // ---- stage data rows y-10..y+10, cols x0-10..x0+73, f16 {d0,d1,d2,0} ----
    for (int e = tid; e < 21 * PWX; e += 256) {
        int r  = e / PWX;                    // compiler magic-div (exact)
        int c  = e - r * PWX;
        int gy = y + r - CC;
        int gx = x0 + c - CC;
        half4v v = (half4v){(_Float16)0, (_Float16)0, (_Float16)0, (_Float16)0};
        if ((unsigned)gy < (unsigned)H && (unsigned)gx < (unsigned)W) {
            v.x = (_Float16)dbase[(0 * H + gy) * W + gx];
            v.y = (_Float16)dbase[(1 * H + gy) * W + gx];
            v.z = (_Float16)dbase[(2 * H + gy) * W + gx];
        }
        *reinterpret_cast<half4v*>(dtB + e * 8) = v;
    }
    __syncthreads();

    // ---- 16 accumulators: 4 px x {ch0, ch1, ch2, w} ----
    float a00 = 0.f, a01 = 0.f, a02 = 0.f, aw0 = 0.f;
    float a10 = 0.f, a11 = 0.f, a12 = 0.f, aw1 = 0.f;
    float a20 = 0.f, a21 = 0.f, a22 = 0.f, aw2 = 0.f;
    float a30 = 0.f, a31 = 0.f, a32 = 0.f, aw3 = 0.f;

    const int ntap = (w <= 8) ? 28 : 27;     // T = w + 16k <= 440
    int i = 0, j = w, Q = 440 - w;           // T = w initially (w < 21)
    #pragma unroll 4
    for (int k = 0; k < ntap; ++k) {
        int py = y + i - CC;
        bool rv = (unsigned)py < (unsigned)H;
        int pyc = py < 0 ? 0 : (py > H - 1 ? H - 1 : py);
        int c0 = x0 + 4 * t + j - CC;        // global kern/data col of elem 0
        // In-bounds: Q>=1 whenever c0<0 (j=0 => T<=420); at Q=440, pyc<=117.
        f4u g = *reinterpret_cast<const f4u*>(
            kbase + ((Q << 14) + (pyc << 7) + c0));
        float e0 = (rv && (unsigned)(c0 + 0) < (unsigned)W) ? __expf(g.v[0]) : 0.f;
        float e1 = (rv && (unsigned)(c0 + 1) < (unsigned)W) ? __expf(g.v[1]) : 0.f;
        float e2 = (rv && (unsigned)(c0 + 2) < (unsigned)W) ? __expf(g.v[2]) : 0.f;
        float e3 = (rv && (unsigned)(c0 + 3) < (unsigned)W) ? __expf(g.v[3]) : 0.f;
        const unsigned char* dp = dtB + (unsigned)(i * PWX + 4 * t + j) * 8;
        half4v d0 = *reinterpret_cast<const half4v*>(dp +  0);
        half4v d1 = *reinterpret_cast<const half4v*>(dp +  8);
        half4v d2 = *reinterpret_cast<const half4v*>(dp + 16);
        half4v d3 = *reinterpret_cast<const half4v*>(dp + 24);
        a00 += e0 * (float)d0.x; a01 += e0 * (float)d0.y; a02 += e0 * (float)d0.z; aw0 += e0;
        a10 += e1 * (float)d1.x; a11 += e1 * (float)d1.y; a12 += e1 * (float)d1.z; aw1 += e1;
        a20 += e2 * (float)d2.x; a21 += e2 * (float)d2.y; a22 += e2 * (float)d2.z; aw2 += e2;
        a30 += e3 * (float)d3.x; a31 += e3 * (float)d3.y; a32 += e3 * (float)d3.z; aw3 += e3;
        // advance T += 16: j += 16 (mod 21), Q -= 16
        j += 16; Q -= 16;
        if (j >= KS) { j -= KS; ++i; }       // wraps at most once (16 < 21)
    }

    // ---- fixed-order cross-worker reduce (sacc aliases the data tile) ----
    __syncthreads();                          // all dt reads done
    float4* sacc = (float4*)smem;             // [16][65] float4, padded stride
    sacc[w * 65 + 4 * t + 0] = make_float4(a00, a01, a02, aw0);
    sacc[w * 65 + 4 * t + 1] = make_float4(a10, a11, a12, aw1);
    sacc[w * 65 + 4 * t + 2] = make_float4(a20, a21, a22, aw2);
    sacc[w * 65 + 4 * t + 3] = make_float4(a30, a31, a32, aw3);
    __syncthreads();
    if (tid < HWX) {
        const int lp = tid;
        const int px = x0 + lp;
        float r0 = 0.f, r1 = 0.f, r2 = 0.f, rw = 0.f;
        #pragma unroll
        for (int s = 0; s < 16; ++s) {        // fixed order -> deterministic
            float4 p = sacc[s * 65 + lp];
            r0 += p.x; r1 += p.y; r2 += p.z; rw += p.w;
        }
        // OOB taps contribute exp(0)=1 each to the softmax denominator
        int nry = max(0, CC - y)  + max(0, y  - (H - 1 - CC));
        int nrx = max(0, CC - px) + max(0, px - (W - 1 - CC));
        float co = 21.f * nry + (float)((21 - nry) * nrx);
        float inv = 1.0f / (rw + co);
        const size_t o = (size_t)b * NCH * HW + (size_t)y * W + px;
        out[o]          = r0 * inv;
        out[o + HW]     = r1 * inv;
        out[o + 2 * HW] = r2 * inv;
        sumw[(size_t)b * HW + (size_t)y * W + px] = rw * inv;
    }
}

extern "C" void kernel_launch(void* const* d_in, const int* in_sizes, int n_in,
                              void* d_out, int out_size, void* d_ws, size_t ws_size,
                              hipStream_t stream)
{
    const float* data = (const float*)d_in[0];   // (4,3,128,128) f32
    const float* kern = (const float*)d_in[1];   // (4,441,128,128) f32
    float* out  = (float*)d_out;                 // (4,3,128,128)
    float* sumw = out + (size_t)B * NCH * HW;    // (4,1,128,128)

    dim3 g(H, 2, B);
    kaw_gather<<<g, 256, 0, stream>>>(data, kern, out, sumw);
}

// Round 16
// 30.506 us; speedup vs baseline: 5.1093x; 1.0052x over previous
//
#include <hip/hip_runtime.h>

#define KS 21
#define CC 10
#define H 128
#define W 128
#define HW (H*W)
#define NCH 3
#define B 4
#define NSPLIT 4               // x-splits per row
#define HWX 32                 // px per block
#define PWX (HWX + 2*CC)       // 52 data slots per staged row

typedef _Float16 half4v __attribute__((ext_vector_type(4)));
struct __attribute__((packed)) f4u { float v[4]; };   // 4B-aligned 16B load

// LDS: dt[21][PWX] packed half4 {d0,d1,d2,0} = 8736 B; sacc [32][33] float4
// = 16896 B aliases it after a barrier. Size = max of the two.
#define SMEM_BYTES (32*33*16)

// grid (H, 4, B), block 256 = 32 workers x 8 px-quads. Block = one quarter-row
// (b, y, x0=32*zh). Worker w takes flattened taps T = w, w+32, ... (<441);
// quad t owns px x0+4t..x0+4t+3. Tap T: kern plane Q = 440-T, row
// py = y + T/21 - 10, cols c0..c0+3 (c0 = x0+4t+(T%21)-10) — one coalesced
// dwordx4 per tap straight from global (each kern byte read once chip-wide).
// (i,j,Q) maintained incrementally (no divisions). Data from a packed-f16
// LDS tile. Epilogue: fixed-order 32-worker in-LDS reduce + closed-form OOB
// denominator + divide. No atomics, no fences, fully deterministic.
__global__ __launch_bounds__(256, 8)
void kaw_gather(const float* __restrict__ data,
                const float* __restrict__ kern,
                float* __restrict__ out,
                float* __restrict__ sumw)
{
    __shared__ __align__(16) unsigned char smem[SMEM_BYTES];
    unsigned char* dtB = smem;

    const int tid = threadIdx.x;
    const int w  = tid >> 3;        // tap worker 0..31
    const int t  = tid & 7;         // px quad within the quarter-row
    const int y  = blockIdx.x;
    const int x0 = blockIdx.y * HWX;
    const int b  = blockIdx.z;

    const float* __restrict__ kbase = kern + (size_t)b * (KS * KS) * HW;
    const float* __restrict__ dbase = data + (size_t)b * NCH * HW;

    // ---- stage data rows y-10..y+10, cols x0-10..x0+41, f16 {d0,d1,d2,0} ----
    for (int e = tid; e < 21 * PWX; e += 256) {
        int r  = e / PWX;                    // compiler magic-div (exact)
        int c  = e - r * PWX;
        int gy = y + r - CC;
        int gx = x0 + c - CC;
        half4v v = (half4v){(_Float16)0, (_Float16)0, (_Float16)0, (_Float16)0};
        if ((unsigned)gy < (unsigned)H && (unsigned)gx < (unsigned)W) {
            v.x = (_Float16)dbase[(0 * H + gy) * W + gx];
            v.y = (_Float16)dbase[(1 * H + gy) * W + gx];
            v.z = (_Float16)dbase[(2 * H + gy) * W + gx];
        }
        *reinterpret_cast<half4v*>(dtB + e * 8) = v;
    }
    __syncthreads();

    // ---- 16 accumulators: 4 px x {ch0, ch1, ch2, w} ----
    float a00 = 0.f, a01 = 0.f, a02 = 0.f, aw0 = 0.f;
    float a10 = 0.f, a11 = 0.f, a12 = 0.f, aw1 = 0.f;
    float a20 = 0.f, a21 = 0.f, a22 = 0.f, aw2 = 0.f;
    float a30 = 0.f, a31 = 0.f, a32 = 0.f, aw3 = 0.f;

    // 441 = 32*13 + 25: workers 0..24 take 14 taps, 25..31 take 13.
    const int ntap = (w < 25) ? 14 : 13;
    int i = (w >= KS) ? 1 : 0;
    int j = (w >= KS) ? w - KS : w;
    int Q = 440 - w;
    #pragma unroll 4
    for (int k = 0; k < ntap; ++k) {
        int py = y + i - CC;
        bool rv = (unsigned)py < (unsigned)H;
        int pyc = py < 0 ? 0 : (py > H - 1 ? H - 1 : py);
        int c0 = x0 + 4 * t + j - CC;        // global kern/data col of elem 0
        // c0 < 0 only when x0==0, where Q >= 1 -> address stays in-bounds.
        f4u g = *reinterpret_cast<const f4u*>(
            kbase + ((Q << 14) + (pyc << 7) + c0));
        float e0 = (rv && (unsigned)(c0 + 0) < (unsigned)W) ? __expf(g.v[0]) : 0.f;
        float e1 = (rv && (unsigned)(c0 + 1) < (unsigned)W) ? __expf(g.v[1]) : 0.f;
        float e2 = (rv && (unsigned)(c0 + 2) < (unsigned)W) ? __expf(g.v[2]) : 0.f;
        float e3 = (rv && (unsigned)(c0 + 3) < (unsigned)W) ? __expf(g.v[3]) : 0.f;
        const unsigned char* dp = dtB + (unsigned)(i * PWX + 4 * t + j) * 8;
        half4v d0 = *reinterpret_cast<const half4v*>(dp +  0);
        half4v d1 = *reinterpret_cast<const half4v*>(dp +  8);
        half4v d2 = *reinterpret_cast<const half4v*>(dp + 16);
        half4v d3 = *reinterpret_cast<const half4v*>(dp + 24);
        a00 += e0 * (float)d0.x; a01 += e0 * (float)d0.y; a02 += e0 * (float)d0.z; aw0 += e0;
        a10 += e1 * (float)d1.x; a11 += e1 * (float)d1.y; a12 += e1 * (float)d1.z; aw1 += e1;
        a20 += e2 * (float)d2.x; a21 += e2 * (float)d2.y; a22 += e2 * (float)d2.z; aw2 += e2;
        a30 += e3 * (float)d3.x; a31 += e3 * (float)d3.y; a32 += e3 * (float)d3.z; aw3 += e3;
        // advance T += 32: j += 32 (mod 21, wraps at most twice), Q -= 32
        j += 32; Q -= 32;
        if (j >= KS) { j -= KS; ++i; }
        if (j >= KS) { j -= KS; ++i; }
    }

    // ---- fixed-order cross-worker reduce (sacc aliases the data tile) ----
    __syncthreads();                          // all dt reads done
    float4* sacc = (float4*)smem;             // [32][33] float4, padded stride
    sacc[w * 33 + 4 * t + 0] = make_float4(a00, a01, a02, aw0);
    sacc[w * 33 + 4 * t + 1] = make_float4(a10, a11, a12, aw1);
    sacc[w * 33 + 4 * t + 2] = make_float4(a20, a21, a22, aw2);
    sacc[w * 33 + 4 * t + 3] = make_float4(a30, a31, a32, aw3);
    __syncthreads();
    if (tid < HWX) {
        const int lp = tid;
        const int px = x0 + lp;
        float r0 = 0.f, r1 = 0.f, r2 = 0.f, rw = 0.f;
        #pragma unroll
        for (int s = 0; s < 32; ++s) {        // fixed order -> deterministic
            float4 p = sacc[s * 33 + lp];
            r0 += p.x; r1 += p.y; r2 += p.z; rw += p.w;
        }
        // OOB taps contribute exp(0)=1 each to the softmax denominator
        int nry = max(0, CC - y)  + max(0, y  - (H - 1 - CC));
        int nrx = max(0, CC - px) + max(0, px - (W - 1 - CC));
        float co = 21.f * nry + (float)((21 - nry) * nrx);
        float inv = 1.0f / (rw + co);
        const size_t o = (size_t)b * NCH * HW + (size_t)y * W + px;
        out[o]          = r0 * inv;
        out[o + HW]     = r1 * inv;
        out[o + 2 * HW] = r2 * inv;
        sumw[(size_t)b * HW + (size_t)y * W + px] = rw * inv;
    }
}

extern "C" void kernel_launch(void* const* d_in, const int* in_sizes, int n_in,
                              void* d_out, int out_size, void* d_ws, size_t ws_size,
                              hipStream_t stream)
{
    const float* data = (const float*)d_in[0];   // (4,3,128,128) f32
    const float* kern = (const float*)d_in[1];   // (4,441,128,128) f32
    float* out  = (float*)d_out;                 // (4,3,128,128)
    float* sumw = out + (size_t)B * NCH * HW;    // (4,1,128,128)

    dim3 g(H, NSPLIT, B);
    kaw_gather<<<g, 256, 0, stream>>>(data, kern, out, sumw);
}